// Round 4
// baseline (230.754 us; speedup 1.0000x reference)
//
#include <hip/hip_runtime.h>

#define NBINS 256
#define NWAVES 4          // 256 threads / 64 lanes
#define BLOCK 256
#define GRID 2048

// torch.histc semantics: width = (255-0)/256 = 0.99609375; idx = floor(x/width);
// x==255 -> last bin; x outside [0,255] dropped. Scale = 1/width = 256/255.
#define BIN_SCALE (256.0f / 255.0f)

// d_out is poisoned before timed replays -> zero all 512 floats ourselves.
__global__ void zero_out(float* __restrict__ out) {
    const int i = blockIdx.x * blockDim.x + threadIdx.x;
    if (i < 2 * NBINS) out[i] = 0.0f;
}

__device__ __forceinline__ void bin_one(float v, unsigned int* sh_wave) {
    if (v >= 0.0f && v <= 255.0f) {
        int idx = (int)(v * BIN_SCALE);
        atomicAdd(&sh_wave[min(idx, NBINS - 1)], 1u);
    }
}

__global__ __launch_bounds__(BLOCK) void hist_kernel(const float* __restrict__ x,
                                                     float* __restrict__ out,
                                                     int n) {
    __shared__ unsigned int sh[NWAVES][NBINS];  // one sub-hist per wave
    unsigned int* sh_wave = sh[threadIdx.x >> 6];

    for (int i = threadIdx.x; i < NWAVES * NBINS; i += BLOCK)
        ((unsigned int*)sh)[i] = 0u;
    __syncthreads();

    const int n4 = n >> 2;
    const float4* __restrict__ x4 = (const float4*)x;
    const int tid = blockIdx.x * BLOCK + threadIdx.x;
    const int stride = gridDim.x * BLOCK;

    for (int i = tid; i < n4; i += stride) {
        float4 v = x4[i];
        bin_one(v.x, sh_wave);
        bin_one(v.y, sh_wave);
        bin_one(v.z, sh_wave);
        bin_one(v.w, sh_wave);
    }

    // scalar tail (n not divisible by 4)
    for (int i = (n4 << 2) + tid; i < n; i += stride)
        bin_one(x[i], sh_wave);

    __syncthreads();

    // reduce 4 sub-hists; one global float atomic per bin per block.
    // Exact: integer-valued floats, totals < 2^24.
    for (int b = threadIdx.x; b < NBINS; b += BLOCK) {
        unsigned int s = sh[0][b] + sh[1][b] + sh[2][b] + sh[3][b];
        if (s) atomicAdd(&out[b], (float)s);
    }
}

__global__ void count_kernel(const void* __restrict__ bs_raw,
                             float* __restrict__ out) {
    // batchsize scalar: int32 expected; hedge for float32 bits.
    const int as_int = *(const int*)bs_raw;
    float bs;
    if (as_int >= 1 && as_int < (1 << 20)) {
        bs = (float)as_int;
    } else {
        bs = *(const float*)bs_raw;
    }
    out[NBINS + threadIdx.x] = bs * out[0];
}

extern "C" void kernel_launch(void* const* d_in, const int* in_sizes, int n_in,
                              void* d_out, int out_size, void* d_ws, size_t ws_size,
                              hipStream_t stream) {
    // The 1-element input is the batchsize scalar; the big one is x.
    const void* bs_ptr;
    const float* x;
    int n;
    if (n_in >= 2 && in_sizes[0] == 1) {
        bs_ptr = d_in[0];
        x = (const float*)d_in[1];
        n = in_sizes[1];
    } else {
        bs_ptr = d_in[1];
        x = (const float*)d_in[0];
        n = in_sizes[0];
    }

    float* out = (float*)d_out;  // [256 hist | 256 count], float32

    zero_out<<<2, 256, 0, stream>>>(out);
    hist_kernel<<<GRID, BLOCK, 0, stream>>>(x, out, n);
    count_kernel<<<1, NBINS, 0, stream>>>(bs_ptr, out);
}